// Round 5
// baseline (446.821 us; speedup 1.0000x reference)
//
#include <hip/hip_runtime.h>

// Sizes: B=4, SEQ=128, D=64, H=512
// out layout (floats): G[16384] | Gamma[1048576] | riemann[67108864] | ricci[16384] | scalar[4] | x[32768]

#define EPSF 1e-6f

typedef unsigned short u16;
typedef __attribute__((ext_vector_type(8))) short short8v;
typedef __attribute__((ext_vector_type(4))) float f32x4v;
typedef __attribute__((ext_vector_type(2))) double d64x2;

__device__ __forceinline__ u16 f2bf_rne(float f) {
  unsigned u = __float_as_uint(f);
  return (u16)((u + 0x7FFFu + ((u >> 16) & 1u)) >> 16);
}

// ---------------- K_front: mlp + L + G + Ginv fused (block = batch b, 512 thr) ----------------
__global__ __launch_bounds__(512) void k_front(const float* __restrict__ x,
    const float* __restrict__ W1, const float* __restrict__ b1,
    const float* __restrict__ W2, const float* __restrict__ b2,
    const float* __restrict__ W3, const float* __restrict__ b3,
    float* __restrict__ Gout, float* __restrict__ Ginv) {
  int b = blockIdx.x;
  int t = threadIdx.x;
  __shared__ union {
    struct { float h0[64]; float h1[512]; float h2[512]; float Ls[64 * 65]; } a;
    struct { double M[64][128]; double prbuf[2][128]; double pvbuf[2]; } inv;
  } sm;
  // phase 1: mean pool + layer1
  if (t < 64) {
    const float* xb = x + b * 8192;
    float s = 0.f;
    #pragma unroll 8
    for (int qq = 0; qq < 128; ++qq) s += xb[qq * 64 + t];
    sm.a.h0[t] = s * (1.f / 128.f);
  }
  __syncthreads();
  {
    float acc = b1[t];
    #pragma unroll 8
    for (int d = 0; d < 64; ++d) acc = fmaf(sm.a.h0[d], W1[d * 512 + t], acc);
    sm.a.h1[t] = fmaxf(acc, 0.f);
  }
  __syncthreads();
  // phase 2: layer2
  {
    float acc = b2[t];
    #pragma unroll 8
    for (int k = 0; k < 512; ++k) acc = fmaf(sm.a.h1[k], W2[k * 512 + t], acc);
    sm.a.h2[t] = fmaxf(acc, 0.f);
  }
  __syncthreads();
  // phase 3: L = tril(h2 @ W3 + b3)
  #pragma unroll
  for (int q = 0; q < 8; ++q) {
    int e = q * 512 + t;
    int i = e >> 6, j = e & 63;
    float acc = 0.f;
    if (j <= i) {
      acc = b3[e];
      #pragma unroll 8
      for (int k = 0; k < 512; ++k) acc = fmaf(sm.a.h2[k], W3[k * 4096 + e], acc);
    }
    sm.a.Ls[i * 65 + j] = acc;
  }
  __syncthreads();
  // phase 4: G = L L^T + eps I (kept in registers for inv init)
  float Gv[8];
  #pragma unroll
  for (int q = 0; q < 8; ++q) {
    int e = q * 512 + t;
    int i = e >> 6, j = e & 63;
    float acc = (i == j) ? EPSF : 0.f;
    #pragma unroll 8
    for (int k = 0; k < 64; ++k) acc = fmaf(sm.a.Ls[i * 65 + k], sm.a.Ls[j * 65 + k], acc);
    Gv[q] = acc;
    Gout[b * 4096 + e] = acc;
  }
  __syncthreads(); // all Ls reads done; overlay union with M
  // phase 5: Gauss-Jordan inverse in double (SPD, no pivoting); batched-register form
  #pragma unroll
  for (int q = 0; q < 8; ++q) {
    int e = q * 512 + t;
    int i = e >> 6, j = e & 63;
    sm.inv.M[i][j] = (double)Gv[q];
    sm.inv.M[i][64 + j] = (i == j) ? 1.0 : 0.0;
  }
  __syncthreads();
  if (t < 64) {
    sm.inv.prbuf[0][2 * t]     = sm.inv.M[0][2 * t];
    sm.inv.prbuf[0][2 * t + 1] = sm.inv.M[0][2 * t + 1];
  }
  if (t == 0) sm.inv.pvbuf[0] = sm.inv.M[0][0];
  __syncthreads();
  int cl = (t & 63) * 2;
  int R0 = (t >> 6) * 8;
  for (int p = 0; p < 64; ++p) {
    int cur = p & 1, nxt = cur ^ 1;
    double pv   = sm.inv.pvbuf[cur];
    double prv0 = sm.inv.prbuf[cur][cl];
    double prv1 = sm.inv.prbuf[cur][cl + 1];
    double fac[8];
    d64x2 av[8];
    #pragma unroll
    for (int q = 0; q < 8; ++q) fac[q] = sm.inv.M[R0 + q][p];          // wave-uniform broadcast
    #pragma unroll
    for (int q = 0; q < 8; ++q) av[q] = *(const d64x2*)&sm.inv.M[R0 + q][cl];
    double pivinv = 1.0 / pv;
    #pragma unroll
    for (int q = 0; q < 8; ++q) {
      int r = R0 + q;
      double f = (r == p) ? (1.0 - pivinv) : fac[q] * pivinv;
      double n0 = av[q].x - f * prv0;
      double n1 = av[q].y - f * prv1;
      d64x2 nv; nv.x = n0; nv.y = n1;
      *(d64x2*)&sm.inv.M[r][cl] = nv;
      if (r == p + 1) {
        sm.inv.prbuf[nxt][cl]     = n0;
        sm.inv.prbuf[nxt][cl + 1] = n1;
        if (cl == ((p + 1) & 62)) sm.inv.pvbuf[nxt] = ((p + 1) & 1) ? n1 : n0;
      }
    }
    __syncthreads();
  }
  for (int e = t; e < 4096; e += 512)
    Ginv[b * 4096 + e] = (float)sm.inv.M[e >> 6][64 + (e & 63)];
}

// ---------------- K_gamma2: Gamma, parallel over (i,b) ----------------
__global__ void k_gamma2(const float* __restrict__ G, const float* __restrict__ Ginv,
                         float* __restrict__ GammaOut) {
  int i = blockIdx.x, b = blockIdx.y;
  int t = threadIdx.x; // 256
  __shared__ float Gs[64 * 65];
  __shared__ float gi[64];
  __shared__ float T1[64];
  __shared__ float T2[64];
  __shared__ float svs;
  for (int e = t; e < 4096; e += 256)
    Gs[(e >> 6) * 65 + (e & 63)] = G[b * 4096 + e];
  if (t < 64) gi[t] = Ginv[b * 4096 + i * 64 + t];
  __syncthreads();
  if (t < 64) {
    float acc = 0.f, acc2 = 0.f;
    #pragma unroll 8
    for (int m = 0; m < 64; ++m) {
      acc  = fmaf(gi[m], Gs[((m - 1) & 63) * 65 + t], acc);
      acc2 = fmaf(gi[m], Gs[t * 65 + ((m - 1) & 63)], acc2);
    }
    T1[t] = acc;
    T2[t] = acc2;
    if (t == 0) {
      float s = 0.f;
      for (int m = 0; m < 64; ++m) s += gi[m];
      svs = s;
    }
  }
  __syncthreads();
  float sv = svs;
  float* o = GammaOut + b * 262144 + i * 4096;
  #pragma unroll
  for (int p = 0; p < 16; ++p) {
    int e = p * 256 + t;
    int jj = e >> 6, k = e & 63;
    o[e] = 0.5f * (T1[k] + T2[jj] - sv * Gs[jj * 65 + k]);
  }
}

// ---------------- K_prep2: Gamma -> transposed bf16 hi/lo planes, + x copy ----------------
__global__ void k_prep2(const float* __restrict__ Gamma,
                        u16* __restrict__ Tah, u16* __restrict__ Tal,
                        u16* __restrict__ Tbh, u16* __restrict__ Tbl,
                        const float* __restrict__ x, float* __restrict__ Xout) {
  int s = blockIdx.x, b = blockIdx.y;
  int t = threadIdx.x; // 256
  __shared__ float Ls[64 * 65];
  // fold in the x copy (256 blocks x 128 floats)
  {
    int gblk = b * 64 + s;
    if (t < 128) Xout[gblk * 128 + t] = x[gblk * 128 + t];
  }
  const float* Gb = Gamma + b * 262144;
  int base = (b * 64 + s) << 12;
  // Phase A: transpose contiguous slice Gamma[b,s,:,:]
  for (int p = 0; p < 16; ++p) {
    int e = p * 256 + t;
    Ls[(e >> 6) * 65 + (e & 63)] = Gb[s * 4096 + e];
  }
  __syncthreads();
  for (int p = 0; p < 16; ++p) {
    int e = p * 256 + t;
    int k = e >> 6, m = e & 63;
    float f = Ls[m * 65 + k];
    u16 hi = f2bf_rne(f);
    float fl = f - __uint_as_float(((unsigned)hi) << 16);
    u16 lo = f2bf_rne(fl);
    Tah[base + e] = hi;
    Tal[base + e] = lo;
  }
  __syncthreads();
  // Phase B: gather Gamma[b,:,s,:], transpose, swizzle
  for (int p = 0; p < 16; ++p) {
    int e = p * 256 + t;
    int m = e >> 6, l = e & 63;
    Ls[m * 65 + l] = Gb[m * 4096 + s * 64 + l];
  }
  __syncthreads();
  for (int p = 0; p < 16; ++p) {
    int e = p * 256 + t;
    int l = e >> 6, m = e & 63;
    float f = Ls[m * 65 + l];
    u16 hi = f2bf_rne(f);
    float fl = f - __uint_as_float(((unsigned)hi) << 16);
    u16 lo = f2bf_rne(fl);
    int idx = base + l * 64 + (((m >> 3) ^ (l & 7)) << 3) + (m & 7);
    Tbh[idx] = hi;
    Tbl[idx] = lo;
  }
}

// ---------------- K6 (MFMA): riemann via split-bf16 MFMA (verified) ----------------
__global__ void k_riemann2(const float* __restrict__ Gamma,
                           const u16* __restrict__ Tah, const u16* __restrict__ Tal,
                           const u16* __restrict__ Tbh, const u16* __restrict__ Tbl,
                           float* __restrict__ R) {
  int j = blockIdx.x, i = blockIdx.y, b = blockIdx.z;
  int t = threadIdx.x; // 256
  __shared__ __align__(16) char smem[64 * 68 * 4];
  __shared__ float dvec[64];
  u16* sBh = (u16*)smem;
  u16* sBl = sBh + 4096;
  float* sU = (float*)smem;

  {
    const u16* pbh = Tbh + ((b * 64 + j) << 12);
    const u16* pbl = Tbl + ((b * 64 + j) << 12);
    #pragma unroll
    for (int p = 0; p < 2; ++p) {
      int g = (p << 8) + t;
      *(short8v*)(sBh + (g << 3)) = *(const short8v*)(pbh + (g << 3));
      *(short8v*)(sBl + (g << 3)) = *(const short8v*)(pbl + (g << 3));
    }
  }
  if (t < 64) {
    const float* Gp = Gamma + ((b + 3) & 3) * 262144 + i * 4096 + j * 64;
    const float* Gc = Gamma + b * 262144 + i * 4096 + j * 64;
    dvec[t] = Gp[t] - Gc[t];
  }

  int lane = t & 63, wv = t >> 6;
  int li = lane & 15, lg = lane >> 4;
  const u16* tah = Tah + (((b * 64 + i) << 12) + (16 * wv + li) * 64 + 8 * lg);
  const u16* tal = Tal + (((b * 64 + i) << 12) + (16 * wv + li) * 64 + 8 * lg);
  short8v aH0 = *(const short8v*)(tah);
  short8v aH1 = *(const short8v*)(tah + 32);
  short8v aL0 = *(const short8v*)(tal);
  short8v aL1 = *(const short8v*)(tal + 32);

  __syncthreads();

  f32x4v acc[4];
  #pragma unroll
  for (int tc = 0; tc < 4; ++tc) {
    acc[tc] = (f32x4v){0.f, 0.f, 0.f, 0.f};
    int rb = 16 * tc + li;
    int rx = rb & 7;
    int off0 = rb * 64 + ((lg ^ rx) << 3);
    int off1 = rb * 64 + (((4 + lg) ^ rx) << 3);
    short8v bH0 = *(const short8v*)(sBh + off0);
    short8v bL0 = *(const short8v*)(sBl + off0);
    short8v bH1 = *(const short8v*)(sBh + off1);
    short8v bL1 = *(const short8v*)(sBl + off1);
    acc[tc] = __builtin_amdgcn_mfma_f32_16x16x32_bf16(aH0, bH0, acc[tc], 0, 0, 0);
    acc[tc] = __builtin_amdgcn_mfma_f32_16x16x32_bf16(aL0, bH0, acc[tc], 0, 0, 0);
    acc[tc] = __builtin_amdgcn_mfma_f32_16x16x32_bf16(aH0, bL0, acc[tc], 0, 0, 0);
    acc[tc] = __builtin_amdgcn_mfma_f32_16x16x32_bf16(aH1, bH1, acc[tc], 0, 0, 0);
    acc[tc] = __builtin_amdgcn_mfma_f32_16x16x32_bf16(aL1, bH1, acc[tc], 0, 0, 0);
    acc[tc] = __builtin_amdgcn_mfma_f32_16x16x32_bf16(aH1, bL1, acc[tc], 0, 0, 0);
  }
  __syncthreads();
  #pragma unroll
  for (int tc = 0; tc < 4; ++tc) {
    #pragma unroll
    for (int r = 0; r < 4; ++r)
      sU[(16 * wv + 4 * lg + r) * 68 + 16 * tc + li] = acc[tc][r];
  }
  __syncthreads();

  int tx = t & 15, ty = t >> 4;
  int l0 = 4 * tx, k0 = 4 * ty;
  float mir[4][4];
  #pragma unroll
  for (int r = 0; r < 4; ++r) {
    float4 v = *(const float4*)(sU + (l0 + r) * 68 + k0);
    mir[r][0] = v.x; mir[r][1] = v.y; mir[r][2] = v.z; mir[r][3] = v.w;
  }
  float dl0 = dvec[l0], dl1 = dvec[l0 + 1], dl2 = dvec[l0 + 2], dl3 = dvec[l0 + 3];
  float* Rout = R + (((size_t)((b * 64 + i) * 64 + j)) << 12);
  #pragma unroll
  for (int q = 0; q < 4; ++q) {
    float4 uq = *(const float4*)(sU + (k0 + q) * 68 + l0);
    float dk = dvec[k0 + q];
    float4 o;
    o.x = uq.x - mir[0][q] + dl0 - dk;
    o.y = uq.y - mir[1][q] + dl1 - dk;
    o.z = uq.z - mir[2][q] + dl2 - dk;
    o.w = uq.w - mir[3][q] + dl3 - dk;
    *(float4*)(Rout + (k0 + q) * 64 + l0) = o;
  }
}

// ---------------- fallback: fp32 VALU riemann ----------------
__global__ void k_riemann_f32(const float* __restrict__ Gamma, float* __restrict__ R) {
  int j = blockIdx.x, i = blockIdx.y, b = blockIdx.z;
  int t = threadIdx.x;
  __shared__ float Ai[64 * 64];
  __shared__ float Bj[64 * 64];
  __shared__ float U[64 * 65];
  __shared__ float dvec[64];
  const float* Gb = Gamma + b * 262144;
  const float* Gbi = Gb + i * 4096;
  for (int e = t; e < 4096; e += 256) Ai[e] = Gbi[e];
  for (int e = t; e < 4096; e += 256) {
    int m = e >> 6, l = e & 63;
    Bj[e] = Gb[m * 4096 + j * 64 + l];
  }
  if (t < 64) {
    const float* Gp = Gamma + ((b + 3) & 3) * 262144 + i * 4096 + j * 64;
    dvec[t] = Gp[t] - Gbi[j * 64 + t];
  }
  __syncthreads();
  int tx = t & 15, ty = t >> 4;
  int k0 = ty * 4, l0 = tx * 4;
  float acc[4][4] = {{0.f}};
  for (int m = 0; m < 64; ++m) {
    float4 a = *(const float4*)(Ai + m * 64 + k0);
    float4 bb = *(const float4*)(Bj + m * 64 + l0);
    acc[0][0] = fmaf(a.x, bb.x, acc[0][0]); acc[0][1] = fmaf(a.x, bb.y, acc[0][1]);
    acc[0][2] = fmaf(a.x, bb.z, acc[0][2]); acc[0][3] = fmaf(a.x, bb.w, acc[0][3]);
    acc[1][0] = fmaf(a.y, bb.x, acc[1][0]); acc[1][1] = fmaf(a.y, bb.y, acc[1][1]);
    acc[1][2] = fmaf(a.y, bb.z, acc[1][2]); acc[1][3] = fmaf(a.y, bb.w, acc[1][3]);
    acc[2][0] = fmaf(a.z, bb.x, acc[2][0]); acc[2][1] = fmaf(a.z, bb.y, acc[2][1]);
    acc[2][2] = fmaf(a.z, bb.z, acc[2][2]); acc[2][3] = fmaf(a.z, bb.w, acc[2][3]);
    acc[3][0] = fmaf(a.w, bb.x, acc[3][0]); acc[3][1] = fmaf(a.w, bb.y, acc[3][1]);
    acc[3][2] = fmaf(a.w, bb.z, acc[3][2]); acc[3][3] = fmaf(a.w, bb.w, acc[3][3]);
  }
  for (int q = 0; q < 4; ++q)
    for (int r = 0; r < 4; ++r)
      U[(k0 + q) * 65 + (l0 + r)] = acc[q][r];
  __syncthreads();
  float* Rout = R + (((size_t)((b * 64 + i) * 64 + j)) << 12);
  for (int q = 0; q < 4; ++q) {
    int k = k0 + q;
    float dk = dvec[k];
    float4 o;
    o.x = acc[q][0] - U[(l0 + 0) * 65 + k] + dvec[l0 + 0] - dk;
    o.y = acc[q][1] - U[(l0 + 1) * 65 + k] + dvec[l0 + 1] - dk;
    o.z = acc[q][2] - U[(l0 + 2) * 65 + k] + dvec[l0 + 2] - dk;
    o.w = acc[q][3] - U[(l0 + 3) * 65 + k] + dvec[l0 + 3] - dk;
    *(float4*)(Rout + k * 64 + l0) = o;
  }
}

// ---------------- K_ricci3: self-contained fp32 ricci from Gamma, block=(i,b) ----------------
// ricci[b,i,j] = (SGp[j]-SGc[j]) - (Pprev[i]-Pcur[i]) + sum_m Pcur[m]*sC[m][j] - a4[j]
// SGc[j] = sum_m sC[m][j]; SGp[j] = sum_m Gamma[bp,m,i,j]; Pcur[m] = sum_s Gamma[b,s,m,s]
// a4[j]  = sum_{k,m} sC[m][k]*Gamma[b,k,m,j];  sC[m][k] = Gamma[b,m,i,k]
__global__ void k_ricci3(const float* __restrict__ Gamma, float* __restrict__ ricci) {
  int i = blockIdx.x, b = blockIdx.y;
  int t = threadIdx.x; // 256
  int j = t & 63, q = t >> 6;
  __shared__ float sC[64][65];
  __shared__ float redA[4][64];
  __shared__ float redS[4][64];
  __shared__ float redP[4][64];
  __shared__ float sPc[64];
  __shared__ float tmpP[64];
  const float* Gb = Gamma + b * 262144;
  int bp = (b + 3) & 3;
  const float* Gp = Gamma + bp * 262144;
  for (int e = t; e < 4096; e += 256) {
    int m = e >> 6, k = e & 63;
    sC[m][k] = Gb[m * 4096 + i * 64 + k];
  }
  if (t < 64) tmpP[t] = Gp[t * 4096 + i * 64 + t]; // Gamma[bp,t,i,t]
  __syncthreads();
  float a4p = 0.f, sgp = 0.f, pcp = 0.f;
  for (int mm = 0; mm < 16; ++mm) {
    int m = q * 16 + mm;
    const float* col = Gb + m * 64 + j;
    float partial = 0.f;
    #pragma unroll 8
    for (int k = 0; k < 64; ++k)
      partial = fmaf(sC[m][k], col[(size_t)k * 4096], partial);
    a4p += partial;
    sgp += Gp[m * 4096 + i * 64 + j];
    pcp += Gb[m * 4097 + j * 64];     // Gamma[b,m,j,m]
  }
  redA[q][j] = a4p;
  redS[q][j] = sgp;
  redP[q][j] = pcp;
  __syncthreads();
  if (t < 64) sPc[t] = redP[0][t] + redP[1][t] + redP[2][t] + redP[3][t];
  __syncthreads();
  if (t < 64) {
    float a4  = redA[0][t] + redA[1][t] + redA[2][t] + redA[3][t];
    float SGp = redS[0][t] + redS[1][t] + redS[2][t] + redS[3][t];
    float SGc = 0.f, a3 = 0.f;
    #pragma unroll 8
    for (int m = 0; m < 64; ++m) {
      SGc += sC[m][t];
      a3 = fmaf(sPc[m], sC[m][t], a3);
    }
    float Ppi = 0.f;
    #pragma unroll 8
    for (int s = 0; s < 64; ++s) Ppi += tmpP[s];
    ricci[b * 4096 + i * 64 + t] = (SGp - SGc) - (Ppi - sPc[i]) + a3 - a4;
  }
}

// ---------------- K_scal: scalar curvature ----------------
__global__ void k_scal(const float* __restrict__ ricci, const float* __restrict__ Ginv,
                       float* __restrict__ scal) {
  int b = blockIdx.x;
  int t = threadIdx.x;
  __shared__ float red[256];
  float local = 0.f;
  for (int e = t; e < 4096; e += 256) local += ricci[b * 4096 + e] * Ginv[b * 4096 + e];
  red[t] = local;
  __syncthreads();
  for (int off = 128; off > 0; off >>= 1) {
    if (t < off) red[t] += red[t + off];
    __syncthreads();
  }
  if (t == 0) scal[b] = red[0];
}

// ---------------- fallback x copy ----------------
__global__ void k_copy(const float* __restrict__ x, float* __restrict__ out) {
  int idx = blockIdx.x * 256 + threadIdx.x;
  out[idx] = x[idx];
}

extern "C" void kernel_launch(void* const* d_in, const int* in_sizes, int n_in,
                              void* d_out, int out_size, void* d_ws, size_t ws_size,
                              hipStream_t stream) {
  const float* x  = (const float*)d_in[0];
  const float* W1 = (const float*)d_in[1];
  const float* b1 = (const float*)d_in[2];
  const float* W2 = (const float*)d_in[3];
  const float* b2 = (const float*)d_in[4];
  const float* W3 = (const float*)d_in[5];
  const float* b3 = (const float*)d_in[6];

  float* out   = (float*)d_out;
  float* G     = out;             // 16384
  float* Gamma = out + 16384;     // 1048576
  float* Riem  = out + 1064960;   // 67108864
  float* Ricci = out + 68173824;  // 16384
  float* Scal  = out + 68190208;  // 4
  float* Xout  = out + 68190212;  // 32768

  // ws layout (floats): [18432..34816) Ginv; [34816..) bf16 planes (2 MB each)
  float* ws   = (float*)d_ws;
  float* Ginv = ws + 18432;
  u16* Tah = (u16*)(ws + 34816);
  u16* Tal = Tah + (1 << 20);
  u16* Tbh = Tal + (1 << 20);
  u16* Tbl = Tbh + (1 << 20);
  const size_t need = 34816u * 4u + 4u * (1u << 21); // 8,527,872 B (proven available)

  hipLaunchKernelGGL(k_front,  dim3(4),      dim3(512), 0, stream,
                     x, W1, b1, W2, b2, W3, b3, G, Ginv);
  hipLaunchKernelGGL(k_gamma2, dim3(64, 4),  dim3(256), 0, stream, G, Ginv, Gamma);
  hipLaunchKernelGGL(k_ricci3, dim3(64, 4),  dim3(256), 0, stream, Gamma, Ricci);
  hipLaunchKernelGGL(k_scal,   dim3(4),      dim3(256), 0, stream, Ricci, Ginv, Scal);
  if (ws_size >= need) {
    hipLaunchKernelGGL(k_prep2,    dim3(64, 4),     dim3(256), 0, stream,
                       Gamma, Tah, Tal, Tbh, Tbl, x, Xout);
    hipLaunchKernelGGL(k_riemann2, dim3(64, 64, 4), dim3(256), 0, stream,
                       Gamma, Tah, Tal, Tbh, Tbl, Riem);
  } else {
    hipLaunchKernelGGL(k_copy,        dim3(128),       dim3(256), 0, stream, x, Xout);
    hipLaunchKernelGGL(k_riemann_f32, dim3(64, 64, 4), dim3(256), 0, stream, Gamma, Riem);
  }
}

// Round 6
// 267.057 us; speedup vs baseline: 1.6731x; 1.6731x over previous
//
#include <hip/hip_runtime.h>

// Sizes: B=4, SEQ=128, D=64, H=512
// out layout (floats): G[16384] | Gamma[1048576] | riemann[67108864] | ricci[16384] | scalar[4] | x[32768]

#define EPSF 1e-6f

typedef unsigned short u16;
typedef __attribute__((ext_vector_type(8))) short short8v;
typedef __attribute__((ext_vector_type(4))) float f32x4v;
typedef __attribute__((ext_vector_type(2))) double d64x2;

__device__ __forceinline__ u16 f2bf_rne(float f) {
  unsigned u = __float_as_uint(f);
  return (u16)((u + 0x7FFFu + ((u >> 16) & 1u)) >> 16);
}

// ---------------- K_mlp_a: mean-pool + layer1 (W1 is tiny) ----------------
__global__ void k_mlp_a(const float* __restrict__ x,
                        const float* __restrict__ W1, const float* __restrict__ b1,
                        float* __restrict__ h1out) {
  int b = blockIdx.x;
  int t = threadIdx.x; // 512
  __shared__ float h0[64];
  if (t < 64) {
    const float* xb = x + b * 8192;
    float s = 0.f;
    #pragma unroll 8
    for (int q = 0; q < 128; ++q) s += xb[q * 64 + t];
    h0[t] = s * (1.f / 128.f);
  }
  __syncthreads();
  float acc = b1[t];
  #pragma unroll 8
  for (int d = 0; d < 64; ++d) acc = fmaf(h0[d], W1[d * 512 + t], acc);
  h1out[b * 512 + t] = fmaxf(acc, 0.f);
}

// ---------------- K_h2: layer2, wide grid (8,4) for W2 bandwidth ----------------
__global__ void k_h2(const float* __restrict__ h1all, const float* __restrict__ W2,
                     const float* __restrict__ b2, float* __restrict__ h2out) {
  int o0 = blockIdx.x * 64, b = blockIdx.y;
  int t = threadIdx.x; // 256
  __shared__ float h1[512];
  __shared__ float red[4][64];
  for (int k = t; k < 512; k += 256) h1[k] = h1all[b * 512 + k];
  __syncthreads();
  int o = o0 + (t & 63), q = t >> 6;
  float acc = 0.f;
  #pragma unroll 8
  for (int k = q * 128; k < q * 128 + 128; ++k)
    acc = fmaf(h1[k], W2[k * 512 + o], acc);
  red[q][t & 63] = acc;
  __syncthreads();
  if (t < 64) {
    float v = red[0][t] + red[1][t] + red[2][t] + red[3][t] + b2[o0 + t];
    h2out[b * 512 + o0 + t] = fmaxf(v, 0.f);
  }
}

// ---------------- K_L2: L = tril(h2 @ W3 + b3), batch-fused (W3 read once) ----------------
__global__ void k_L2(const float* __restrict__ h2all, const float* __restrict__ W3,
                     const float* __restrict__ b3, float* __restrict__ Lout) {
  int t = threadIdx.x; // 256, grid 32
  int le = t & 127, half = t >> 7;
  int e = blockIdx.x * 128 + le;
  __shared__ float h[4][512];
  __shared__ float red[4][2][128];
  for (int k = t; k < 2048; k += 256) h[k >> 9][k & 511] = h2all[k];
  __syncthreads();
  int i = e >> 6, j = e & 63;
  float a0 = 0.f, a1 = 0.f, a2 = 0.f, a3 = 0.f;
  if (j <= i) {
    const float* w = W3 + (size_t)half * 256 * 4096 + e;
    const float* hh = &h[0][half * 256];
    #pragma unroll 8
    for (int k = 0; k < 256; ++k) {
      float wv = w[(size_t)k * 4096];
      a0 = fmaf(hh[k], wv, a0);
      a1 = fmaf(hh[512 + k], wv, a1);
      a2 = fmaf(hh[1024 + k], wv, a2);
      a3 = fmaf(hh[1536 + k], wv, a3);
    }
  }
  red[0][half][le] = a0; red[1][half][le] = a1;
  red[2][half][le] = a2; red[3][half][le] = a3;
  __syncthreads();
  if (half == 0) {
    float keep = (j <= i) ? 1.f : 0.f;
    float bb = keep * b3[e];
    #pragma unroll
    for (int bi = 0; bi < 4; ++bi)
      Lout[bi * 4096 + e] = keep * (red[bi][0][le] + red[bi][1][le]) + bb;
  }
}

// ---------------- K3: G = L @ L^T + eps I ----------------
__global__ void k_G(const float* __restrict__ Lin, float* __restrict__ Gout) {
  int b = blockIdx.x;
  __shared__ float Ls[64 * 65];
  for (int e = threadIdx.x; e < 4096; e += 256)
    Ls[(e >> 6) * 65 + (e & 63)] = Lin[b * 4096 + e];
  __syncthreads();
  for (int p = 0; p < 16; ++p) {
    int e = p * 256 + threadIdx.x;
    int i = e >> 6, j = e & 63;
    float acc = (i == j) ? EPSF : 0.f;
    for (int k = 0; k < 64; ++k) acc = fmaf(Ls[i * 65 + k], Ls[j * 65 + k], acc);
    Gout[b * 4096 + e] = acc;
  }
}

// ---------------- K4: Ginv via Gauss-Jordan in double, batched-register form (verified r4) ----------------
__global__ void k_inv(const float* __restrict__ G, float* __restrict__ Ginv) {
  int b = blockIdx.x;
  int t = threadIdx.x; // 256
  __shared__ double M[64][128];
  __shared__ double prbuf[2][128];
  __shared__ double pvbuf[2];
  int cl = (t & 63) * 2;
  int R0 = (t >> 6) * 16;
  for (int e = t; e < 64 * 128; e += 256) {
    int i = e >> 7, jj = e & 127;
    double v;
    if (jj < 64) v = (double)G[b * 4096 + i * 64 + jj];
    else         v = (jj - 64 == i) ? 1.0 : 0.0;
    M[i][jj] = v;
  }
  __syncthreads();
  if (t < 64) {
    prbuf[0][2 * t]     = M[0][2 * t];
    prbuf[0][2 * t + 1] = M[0][2 * t + 1];
  }
  if (t == 0) pvbuf[0] = M[0][0];
  __syncthreads();
  for (int p = 0; p < 64; ++p) {
    int cur = p & 1, nxt = cur ^ 1;
    double pv   = pvbuf[cur];
    double prv0 = prbuf[cur][cl];
    double prv1 = prbuf[cur][cl + 1];
    double fac[16];
    d64x2 av[16];
    #pragma unroll
    for (int q = 0; q < 16; ++q) fac[q] = M[R0 + q][p];
    #pragma unroll
    for (int q = 0; q < 16; ++q) av[q] = *(const d64x2*)&M[R0 + q][cl];
    double pivinv = 1.0 / pv;
    #pragma unroll
    for (int q = 0; q < 16; ++q) {
      int r = R0 + q;
      double f = (r == p) ? (1.0 - pivinv) : fac[q] * pivinv;
      double n0 = av[q].x - f * prv0;
      double n1 = av[q].y - f * prv1;
      d64x2 nv; nv.x = n0; nv.y = n1;
      *(d64x2*)&M[r][cl] = nv;
      if (r == p + 1) {
        prbuf[nxt][cl]     = n0;
        prbuf[nxt][cl + 1] = n1;
        if (cl == ((p + 1) & 62)) pvbuf[nxt] = ((p + 1) & 1) ? n1 : n0;
      }
    }
    __syncthreads();
  }
  for (int e = t; e < 4096; e += 256)
    Ginv[b * 4096 + e] = (float)M[e >> 6][64 + (e & 63)];
}

// ---------------- K_gamma2: Gamma, parallel over (i,b) (verified r5) ----------------
__global__ void k_gamma2(const float* __restrict__ G, const float* __restrict__ Ginv,
                         float* __restrict__ GammaOut) {
  int i = blockIdx.x, b = blockIdx.y;
  int t = threadIdx.x; // 256
  __shared__ float Gs[64 * 65];
  __shared__ float gi[64];
  __shared__ float T1[64];
  __shared__ float T2[64];
  __shared__ float svs;
  for (int e = t; e < 4096; e += 256)
    Gs[(e >> 6) * 65 + (e & 63)] = G[b * 4096 + e];
  if (t < 64) gi[t] = Ginv[b * 4096 + i * 64 + t];
  __syncthreads();
  if (t < 64) {
    float acc = 0.f, acc2 = 0.f;
    #pragma unroll 8
    for (int m = 0; m < 64; ++m) {
      acc  = fmaf(gi[m], Gs[((m - 1) & 63) * 65 + t], acc);
      acc2 = fmaf(gi[m], Gs[t * 65 + ((m - 1) & 63)], acc2);
    }
    T1[t] = acc;
    T2[t] = acc2;
    if (t == 0) {
      float s = 0.f;
      for (int m = 0; m < 64; ++m) s += gi[m];
      svs = s;
    }
  }
  __syncthreads();
  float sv = svs;
  float* o = GammaOut + b * 262144 + i * 4096;
  #pragma unroll
  for (int p = 0; p < 16; ++p) {
    int e = p * 256 + t;
    int jj = e >> 6, k = e & 63;
    o[e] = 0.5f * (T1[k] + T2[jj] - sv * Gs[jj * 65 + k]);
  }
}

// ---------------- K_prep2: Gamma -> transposed bf16 hi/lo planes, + x copy (verified r5) ----------------
__global__ void k_prep2(const float* __restrict__ Gamma,
                        u16* __restrict__ Tah, u16* __restrict__ Tal,
                        u16* __restrict__ Tbh, u16* __restrict__ Tbl,
                        const float* __restrict__ x, float* __restrict__ Xout) {
  int s = blockIdx.x, b = blockIdx.y;
  int t = threadIdx.x; // 256
  __shared__ float Ls[64 * 65];
  {
    int gblk = b * 64 + s;
    if (t < 128) Xout[gblk * 128 + t] = x[gblk * 128 + t];
  }
  const float* Gb = Gamma + b * 262144;
  int base = (b * 64 + s) << 12;
  for (int p = 0; p < 16; ++p) {
    int e = p * 256 + t;
    Ls[(e >> 6) * 65 + (e & 63)] = Gb[s * 4096 + e];
  }
  __syncthreads();
  for (int p = 0; p < 16; ++p) {
    int e = p * 256 + t;
    int k = e >> 6, m = e & 63;
    float f = Ls[m * 65 + k];
    u16 hi = f2bf_rne(f);
    float fl = f - __uint_as_float(((unsigned)hi) << 16);
    u16 lo = f2bf_rne(fl);
    Tah[base + e] = hi;
    Tal[base + e] = lo;
  }
  __syncthreads();
  for (int p = 0; p < 16; ++p) {
    int e = p * 256 + t;
    int m = e >> 6, l = e & 63;
    Ls[m * 65 + l] = Gb[m * 4096 + s * 64 + l];
  }
  __syncthreads();
  for (int p = 0; p < 16; ++p) {
    int e = p * 256 + t;
    int l = e >> 6, m = e & 63;
    float f = Ls[m * 65 + l];
    u16 hi = f2bf_rne(f);
    float fl = f - __uint_as_float(((unsigned)hi) << 16);
    u16 lo = f2bf_rne(fl);
    int idx = base + l * 64 + (((m >> 3) ^ (l & 7)) << 3) + (m & 7);
    Tbh[idx] = hi;
    Tbl[idx] = lo;
  }
}

// ---------------- K6 (MFMA): riemann via split-bf16 MFMA (verified r3) ----------------
__global__ void k_riemann2(const float* __restrict__ Gamma,
                           const u16* __restrict__ Tah, const u16* __restrict__ Tal,
                           const u16* __restrict__ Tbh, const u16* __restrict__ Tbl,
                           float* __restrict__ R) {
  int j = blockIdx.x, i = blockIdx.y, b = blockIdx.z;
  int t = threadIdx.x; // 256
  __shared__ __align__(16) char smem[64 * 68 * 4];
  __shared__ float dvec[64];
  u16* sBh = (u16*)smem;
  u16* sBl = sBh + 4096;
  float* sU = (float*)smem;

  {
    const u16* pbh = Tbh + ((b * 64 + j) << 12);
    const u16* pbl = Tbl + ((b * 64 + j) << 12);
    #pragma unroll
    for (int p = 0; p < 2; ++p) {
      int g = (p << 8) + t;
      *(short8v*)(sBh + (g << 3)) = *(const short8v*)(pbh + (g << 3));
      *(short8v*)(sBl + (g << 3)) = *(const short8v*)(pbl + (g << 3));
    }
  }
  if (t < 64) {
    const float* Gp = Gamma + ((b + 3) & 3) * 262144 + i * 4096 + j * 64;
    const float* Gc = Gamma + b * 262144 + i * 4096 + j * 64;
    dvec[t] = Gp[t] - Gc[t];
  }

  int lane = t & 63, wv = t >> 6;
  int li = lane & 15, lg = lane >> 4;
  const u16* tah = Tah + (((b * 64 + i) << 12) + (16 * wv + li) * 64 + 8 * lg);
  const u16* tal = Tal + (((b * 64 + i) << 12) + (16 * wv + li) * 64 + 8 * lg);
  short8v aH0 = *(const short8v*)(tah);
  short8v aH1 = *(const short8v*)(tah + 32);
  short8v aL0 = *(const short8v*)(tal);
  short8v aL1 = *(const short8v*)(tal + 32);

  __syncthreads();

  f32x4v acc[4];
  #pragma unroll
  for (int tc = 0; tc < 4; ++tc) {
    acc[tc] = (f32x4v){0.f, 0.f, 0.f, 0.f};
    int rb = 16 * tc + li;
    int rx = rb & 7;
    int off0 = rb * 64 + ((lg ^ rx) << 3);
    int off1 = rb * 64 + (((4 + lg) ^ rx) << 3);
    short8v bH0 = *(const short8v*)(sBh + off0);
    short8v bL0 = *(const short8v*)(sBl + off0);
    short8v bH1 = *(const short8v*)(sBh + off1);
    short8v bL1 = *(const short8v*)(sBl + off1);
    acc[tc] = __builtin_amdgcn_mfma_f32_16x16x32_bf16(aH0, bH0, acc[tc], 0, 0, 0);
    acc[tc] = __builtin_amdgcn_mfma_f32_16x16x32_bf16(aL0, bH0, acc[tc], 0, 0, 0);
    acc[tc] = __builtin_amdgcn_mfma_f32_16x16x32_bf16(aH0, bL0, acc[tc], 0, 0, 0);
    acc[tc] = __builtin_amdgcn_mfma_f32_16x16x32_bf16(aH1, bH1, acc[tc], 0, 0, 0);
    acc[tc] = __builtin_amdgcn_mfma_f32_16x16x32_bf16(aL1, bH1, acc[tc], 0, 0, 0);
    acc[tc] = __builtin_amdgcn_mfma_f32_16x16x32_bf16(aH1, bL1, acc[tc], 0, 0, 0);
  }
  __syncthreads();
  #pragma unroll
  for (int tc = 0; tc < 4; ++tc) {
    #pragma unroll
    for (int r = 0; r < 4; ++r)
      sU[(16 * wv + 4 * lg + r) * 68 + 16 * tc + li] = acc[tc][r];
  }
  __syncthreads();

  int tx = t & 15, ty = t >> 4;
  int l0 = 4 * tx, k0 = 4 * ty;
  float mir[4][4];
  #pragma unroll
  for (int r = 0; r < 4; ++r) {
    float4 v = *(const float4*)(sU + (l0 + r) * 68 + k0);
    mir[r][0] = v.x; mir[r][1] = v.y; mir[r][2] = v.z; mir[r][3] = v.w;
  }
  float dl0 = dvec[l0], dl1 = dvec[l0 + 1], dl2 = dvec[l0 + 2], dl3 = dvec[l0 + 3];
  float* Rout = R + (((size_t)((b * 64 + i) * 64 + j)) << 12);
  #pragma unroll
  for (int q = 0; q < 4; ++q) {
    float4 uq = *(const float4*)(sU + (k0 + q) * 68 + l0);
    float dk = dvec[k0 + q];
    float4 o;
    o.x = uq.x - mir[0][q] + dl0 - dk;
    o.y = uq.y - mir[1][q] + dl1 - dk;
    o.z = uq.z - mir[2][q] + dl2 - dk;
    o.w = uq.w - mir[3][q] + dl3 - dk;
    *(float4*)(Rout + (k0 + q) * 64 + l0) = o;
  }
}

// ---------------- fallback: fp32 VALU riemann ----------------
__global__ void k_riemann_f32(const float* __restrict__ Gamma, float* __restrict__ R) {
  int j = blockIdx.x, i = blockIdx.y, b = blockIdx.z;
  int t = threadIdx.x;
  __shared__ float Ai[64 * 64];
  __shared__ float Bj[64 * 64];
  __shared__ float U[64 * 65];
  __shared__ float dvec[64];
  const float* Gb = Gamma + b * 262144;
  const float* Gbi = Gb + i * 4096;
  for (int e = t; e < 4096; e += 256) Ai[e] = Gbi[e];
  for (int e = t; e < 4096; e += 256) {
    int m = e >> 6, l = e & 63;
    Bj[e] = Gb[m * 4096 + j * 64 + l];
  }
  if (t < 64) {
    const float* Gp = Gamma + ((b + 3) & 3) * 262144 + i * 4096 + j * 64;
    dvec[t] = Gp[t] - Gbi[j * 64 + t];
  }
  __syncthreads();
  int tx = t & 15, ty = t >> 4;
  int k0 = ty * 4, l0 = tx * 4;
  float acc[4][4] = {{0.f}};
  for (int m = 0; m < 64; ++m) {
    float4 a = *(const float4*)(Ai + m * 64 + k0);
    float4 bb = *(const float4*)(Bj + m * 64 + l0);
    acc[0][0] = fmaf(a.x, bb.x, acc[0][0]); acc[0][1] = fmaf(a.x, bb.y, acc[0][1]);
    acc[0][2] = fmaf(a.x, bb.z, acc[0][2]); acc[0][3] = fmaf(a.x, bb.w, acc[0][3]);
    acc[1][0] = fmaf(a.y, bb.x, acc[1][0]); acc[1][1] = fmaf(a.y, bb.y, acc[1][1]);
    acc[1][2] = fmaf(a.y, bb.z, acc[1][2]); acc[1][3] = fmaf(a.y, bb.w, acc[1][3]);
    acc[2][0] = fmaf(a.z, bb.x, acc[2][0]); acc[2][1] = fmaf(a.z, bb.y, acc[2][1]);
    acc[2][2] = fmaf(a.z, bb.z, acc[2][2]); acc[2][3] = fmaf(a.z, bb.w, acc[2][3]);
    acc[3][0] = fmaf(a.w, bb.x, acc[3][0]); acc[3][1] = fmaf(a.w, bb.y, acc[3][1]);
    acc[3][2] = fmaf(a.w, bb.z, acc[3][2]); acc[3][3] = fmaf(a.w, bb.w, acc[3][3]);
  }
  for (int q = 0; q < 4; ++q)
    for (int r = 0; r < 4; ++r)
      U[(k0 + q) * 65 + (l0 + r)] = acc[q][r];
  __syncthreads();
  float* Rout = R + (((size_t)((b * 64 + i) * 64 + j)) << 12);
  for (int q = 0; q < 4; ++q) {
    int k = k0 + q;
    float dk = dvec[k];
    float4 o;
    o.x = acc[q][0] - U[(l0 + 0) * 65 + k] + dvec[l0 + 0] - dk;
    o.y = acc[q][1] - U[(l0 + 1) * 65 + k] + dvec[l0 + 1] - dk;
    o.z = acc[q][2] - U[(l0 + 2) * 65 + k] + dvec[l0 + 2] - dk;
    o.w = acc[q][3] - U[(l0 + 3) * 65 + k] + dvec[l0 + 3] - dk;
    *(float4*)(Rout + k * 64 + l0) = o;
  }
}

// ---------------- K_ricci3: self-contained fp32 ricci from Gamma (verified r5) ----------------
__global__ void k_ricci3(const float* __restrict__ Gamma, float* __restrict__ ricci) {
  int i = blockIdx.x, b = blockIdx.y;
  int t = threadIdx.x; // 256
  int j = t & 63, q = t >> 6;
  __shared__ float sC[64][65];
  __shared__ float redA[4][64];
  __shared__ float redS[4][64];
  __shared__ float redP[4][64];
  __shared__ float sPc[64];
  __shared__ float tmpP[64];
  const float* Gb = Gamma + b * 262144;
  int bp = (b + 3) & 3;
  const float* Gp = Gamma + bp * 262144;
  for (int e = t; e < 4096; e += 256) {
    int m = e >> 6, k = e & 63;
    sC[m][k] = Gb[m * 4096 + i * 64 + k];
  }
  if (t < 64) tmpP[t] = Gp[t * 4096 + i * 64 + t];
  __syncthreads();
  float a4p = 0.f, sgp = 0.f, pcp = 0.f;
  for (int mm = 0; mm < 16; ++mm) {
    int m = q * 16 + mm;
    const float* col = Gb + m * 64 + j;
    float partial = 0.f;
    #pragma unroll 8
    for (int k = 0; k < 64; ++k)
      partial = fmaf(sC[m][k], col[(size_t)k * 4096], partial);
    a4p += partial;
    sgp += Gp[m * 4096 + i * 64 + j];
    pcp += Gb[m * 4097 + j * 64];
  }
  redA[q][j] = a4p;
  redS[q][j] = sgp;
  redP[q][j] = pcp;
  __syncthreads();
  if (t < 64) sPc[t] = redP[0][t] + redP[1][t] + redP[2][t] + redP[3][t];
  __syncthreads();
  if (t < 64) {
    float a4  = redA[0][t] + redA[1][t] + redA[2][t] + redA[3][t];
    float SGp = redS[0][t] + redS[1][t] + redS[2][t] + redS[3][t];
    float SGc = 0.f, a3 = 0.f;
    #pragma unroll 8
    for (int m = 0; m < 64; ++m) {
      SGc += sC[m][t];
      a3 = fmaf(sPc[m], sC[m][t], a3);
    }
    float Ppi = 0.f;
    #pragma unroll 8
    for (int s = 0; s < 64; ++s) Ppi += tmpP[s];
    ricci[b * 4096 + i * 64 + t] = (SGp - SGc) - (Ppi - sPc[i]) + a3 - a4;
  }
}

// ---------------- K_scal: scalar curvature ----------------
__global__ void k_scal(const float* __restrict__ ricci, const float* __restrict__ Ginv,
                       float* __restrict__ scal) {
  int b = blockIdx.x;
  int t = threadIdx.x;
  __shared__ float red[256];
  float local = 0.f;
  for (int e = t; e < 4096; e += 256) local += ricci[b * 4096 + e] * Ginv[b * 4096 + e];
  red[t] = local;
  __syncthreads();
  for (int off = 128; off > 0; off >>= 1) {
    if (t < off) red[t] += red[t + off];
    __syncthreads();
  }
  if (t == 0) scal[b] = red[0];
}

// ---------------- fallback x copy ----------------
__global__ void k_copy(const float* __restrict__ x, float* __restrict__ out) {
  int idx = blockIdx.x * 256 + threadIdx.x;
  out[idx] = x[idx];
}

extern "C" void kernel_launch(void* const* d_in, const int* in_sizes, int n_in,
                              void* d_out, int out_size, void* d_ws, size_t ws_size,
                              hipStream_t stream) {
  const float* x  = (const float*)d_in[0];
  const float* W1 = (const float*)d_in[1];
  const float* b1 = (const float*)d_in[2];
  const float* W2 = (const float*)d_in[3];
  const float* b2 = (const float*)d_in[4];
  const float* W3 = (const float*)d_in[5];
  const float* b3 = (const float*)d_in[6];

  float* out   = (float*)d_out;
  float* G     = out;             // 16384
  float* Gamma = out + 16384;     // 1048576
  float* Riem  = out + 1064960;   // 67108864
  float* Ricci = out + 68173824;  // 16384
  float* Scal  = out + 68190208;  // 4
  float* Xout  = out + 68190212;  // 32768

  // ws layout (floats):
  //  [0..2048)       h1 (k_mlp_a -> k_h2)
  //  [2048..18432)   Lbuf (k_L2 -> k_G)
  //  [18432..20480)  h2 (k_h2 -> k_L2); dead before k_inv writes Ginv
  //  [18432..34816)  Ginv (k_inv -> end)
  //  [34816..)       bf16 planes Tah/Tal/Tbh/Tbl (2 MB each)
  float* ws   = (float*)d_ws;
  float* h1   = ws;
  float* Lbuf = ws + 2048;
  float* h2   = ws + 18432;
  float* Ginv = ws + 18432;
  u16* Tah = (u16*)(ws + 34816);
  u16* Tal = Tah + (1 << 20);
  u16* Tbh = Tal + (1 << 20);
  u16* Tbl = Tbh + (1 << 20);
  const size_t need = 34816u * 4u + 4u * (1u << 21); // 8,527,872 B (proven available)

  hipLaunchKernelGGL(k_mlp_a, dim3(4),     dim3(512), 0, stream, x, W1, b1, h1);
  hipLaunchKernelGGL(k_h2,    dim3(8, 4),  dim3(256), 0, stream, h1, W2, b2, h2);
  hipLaunchKernelGGL(k_L2,    dim3(32),    dim3(256), 0, stream, h2, W3, b3, Lbuf);
  hipLaunchKernelGGL(k_G,     dim3(4),     dim3(256), 0, stream, Lbuf, G);
  hipLaunchKernelGGL(k_inv,   dim3(4),     dim3(256), 0, stream, G, Ginv);
  hipLaunchKernelGGL(k_gamma2, dim3(64, 4), dim3(256), 0, stream, G, Ginv, Gamma);
  hipLaunchKernelGGL(k_ricci3, dim3(64, 4), dim3(256), 0, stream, Gamma, Ricci);
  hipLaunchKernelGGL(k_scal,   dim3(4),     dim3(256), 0, stream, Ricci, Ginv, Scal);
  if (ws_size >= need) {
    hipLaunchKernelGGL(k_prep2,    dim3(64, 4),     dim3(256), 0, stream,
                       Gamma, Tah, Tal, Tbh, Tbl, x, Xout);
    hipLaunchKernelGGL(k_riemann2, dim3(64, 64, 4), dim3(256), 0, stream,
                       Gamma, Tah, Tal, Tbh, Tbl, Riem);
  } else {
    hipLaunchKernelGGL(k_copy,        dim3(128),       dim3(256), 0, stream, x, Xout);
    hipLaunchKernelGGL(k_riemann_f32, dim3(64, 64, 4), dim3(256), 0, stream, Gamma, Riem);
  }
}